// Round 22
// baseline (167.174 us; speedup 1.0000x reference)
//
#include <hip/hip_runtime.h>
#include <hip/hip_bf16.h>
#include <math.h>

// AxialShift block: conv1x1 -> GN(1) -> GELU -> 4 axial-shift conv1x1 branches
// (gelu, summed) -> GN(1) -> conv1x1.  B=4, C=96, H=W=256, fp32 in/out.
// Round 22: r21 (best, 156.7us) with k3 back on the WT=32 tile (r5's shape,
// which beat WT16 90.5-vs-95 even unoptimized) now combined with mt-outer:
// 6 weight-frag loads per mt feed 4 nf bodies (96 outputs/thread) -> weight
// load issue+latency per output halves; staging/barrier cost amortized 2x.
// LDS 70.7KB -> 2 blocks/CU.
//   k0: weights->bf16 frag-order | k1: conv1+GN1 raw stats -> ap NHWC bf16
//   k3: staged halo (gelu fused) + 4 shifted convs -> zb + GN2 raw stats
//   k4b: finalize GN2 + fold into W3/b3 (frag-order) | k5: conv3 -> d_out

#define B_ 4
#define C_ 96
#define H_ 256
#define W_ 256
#define NPIX (H_ * W_)
#define GN_N ((float)(C_ * NPIX))
#define CPAD 104  // LDS channel stride in shorts (208B: 16B-aligned, ~2-way banks)
#define WFRAG 9216  // shorts per frag-ordered 96x96 matrix (1152 frags x 8)

// k3 tile: 8 rows x 32 px per block
#define HT 8
#define WT 32
#define HHT (HT + 2)
#define HWT (WT + 2)
#define HALO_PX (HHT * HWT)   // 340
#define GR_PX 12              // 16B granules per pixel (96 ch bf16)
#define ROW_GR (HWT * GR_PX)  // 408
#define TOT_GR (HHT * ROW_GR) // 4080

typedef __attribute__((ext_vector_type(4))) float f32x4;
typedef __attribute__((ext_vector_type(8))) short short8;
typedef __attribute__((ext_vector_type(2))) unsigned int uint2v;
typedef __attribute__((ext_vector_type(4))) unsigned int uint4v;

__device__ __forceinline__ float bf2f(unsigned short u) {
    return __uint_as_float(((unsigned int)u) << 16);
}
__device__ __forceinline__ unsigned short f2bf(float v) {
    unsigned int u = __float_as_uint(v);
    unsigned int r = (u + 0x7FFFu + ((u >> 16) & 1u)) >> 16;
    return (unsigned short)r;
}
// pack two f32 -> two bf16 (RNE) in one op
__device__ __forceinline__ unsigned int cvtpk(float lo, float hi) {
    unsigned int r;
    asm("v_cvt_pk_bf16_f32 %0, %1, %2" : "=v"(r) : "v"(lo), "v"(hi));
    return r;
}

__device__ __forceinline__ float gelu_f(float v) {
    // sigmoid-approx gelu: v * sigmoid(1.702 v) = v * rcp(1 + 2^(-2.455467 v))
    float e = __builtin_amdgcn_exp2f(v * -2.455467f);
    return v * __builtin_amdgcn_rcpf(e + 1.0f);
}

__device__ __forceinline__ float waveReduceSum(float v) {
#pragma unroll
    for (int off = 32; off > 0; off >>= 1) v += __shfl_down(v, off);
    return v;
}

__device__ __forceinline__ f32x4 mfma16(short8 a, short8 b, f32x4 c) {
    return __builtin_amdgcn_mfma_f32_16x16x32_bf16(a, b, c, 0, 0, 0);
}

// coalesced weight-frag load: uniform base + lane*16B
__device__ __forceinline__ short8 wfrag(const unsigned short* __restrict__ wf,
                                        int mt, int kb, int l) {
    return *reinterpret_cast<const short8*>(wf + (((mt * 3 + kb) << 6) + l) * 8);
}

// ------ K0: weights -> bf16 in A-frag order; zero stats ------
// frag f=(mt*3+kb)*64+l, elem j:  w[mt*16+(l&15)][kb*32+(l>>4)*8+j]
__global__ void k0_prep(const float* __restrict__ w1, const float* __restrict__ w21,
                        const float* __restrict__ w22,
                        unsigned short* __restrict__ wf, float* __restrict__ stats) {
    int t = blockIdx.x * 256 + threadIdx.x;
    if (blockIdx.x == 0 && threadIdx.x < 16) stats[threadIdx.x] = 0.f;
    if (t >= 3 * WFRAG) return;
    int m = t / WFRAG, rm = t - m * WFRAG;
    int f = rm >> 3, j = rm & 7;
    int mt = f / 192, rem = f - mt * 192;
    int kb = rem >> 6, l = rem & 63;
    int row = mt * 16 + (l & 15);
    int col = kb * 32 + ((l >> 4) << 3) + j;
    const float* src = (m == 0) ? w1 : (m == 1) ? w21 : w22;
    wf[t] = f2bf(src[row * C_ + col]);
}

// ------- K1: conv1 (MFMA) + GN1 raw stats -> ap NHWC bf16 (pre-gelu) -------
__global__ __launch_bounds__(256, 3) void k1_conv1(
    const float* __restrict__ x, const unsigned short* __restrict__ w1f,
    const float* __restrict__ b1, unsigned short* __restrict__ ap,
    float* __restrict__ stats) {
    __shared__ unsigned short xs[256 * CPAD];
    __shared__ float red[8];
    int tid = threadIdx.x;
    int b = blockIdx.x >> 8;
    int h = blockIdx.x & 255;
    int pix0 = h << 8;
    size_t xbase = (size_t)b * C_ * NPIX + pix0 + tid;
    int lb = tid * CPAD;
    // staging: 3 batches of 32 loads (3 latency events instead of 12)
#pragma unroll
    for (int cc = 0; cc < C_; cc += 32) {
        float f[32];
#pragma unroll
        for (int j = 0; j < 32; ++j) f[j] = x[xbase + (size_t)(cc + j) * NPIX];
#pragma unroll
        for (int p8 = 0; p8 < 4; ++p8) {
            uint4v pk = {cvtpk(f[p8 * 8 + 0], f[p8 * 8 + 1]),
                         cvtpk(f[p8 * 8 + 2], f[p8 * 8 + 3]),
                         cvtpk(f[p8 * 8 + 4], f[p8 * 8 + 5]),
                         cvtpk(f[p8 * 8 + 6], f[p8 * 8 + 7])};
            *reinterpret_cast<uint4v*>(&xs[lb + cc + p8 * 8]) = pk;
        }
    }
    __syncthreads();
    int l = tid & 63, wv = tid >> 6;
    int bx = l & 15, q = l >> 4, cl = q * 8;
    short8 bfr[4][3];
#pragma unroll
    for (int nf = 0; nf < 4; ++nf) {
        int p = (4 * wv + nf) * 16 + bx;
#pragma unroll
        for (int kb = 0; kb < 3; ++kb)
            bfr[nf][kb] = *reinterpret_cast<const short8*>(&xs[p * CPAD + kb * 32 + cl]);
    }
    unsigned int* xsu = reinterpret_cast<unsigned int*>(xs);
    float ls = 0.f, lsq = 0.f;
    for (int mt = 0; mt < 6; ++mt) {
        int m0 = mt * 16;
        short8 af[3];
#pragma unroll
        for (int kb = 0; kb < 3; ++kb) af[kb] = wfrag(w1f, mt, kb, l);
        f32x4 acc[4];
#pragma unroll
        for (int nf = 0; nf < 4; ++nf) acc[nf] = (f32x4){0.f, 0.f, 0.f, 0.f};
#pragma unroll
        for (int nf = 0; nf < 4; ++nf)
#pragma unroll
            for (int kb = 0; kb < 3; ++kb)
                acc[nf] = mfma16(af[kb], bfr[nf][kb], acc[nf]);
        int o = m0 + q * 4;
        float b0 = b1[o], b1v = b1[o + 1], b2v = b1[o + 2], b3v = b1[o + 3];
#pragma unroll
        for (int nf = 0; nf < 4; ++nf) {
            int p = (4 * wv + nf) * 16 + bx;  // own wave stripe: race-free
            float y0 = acc[nf][0] + b0, y1v = acc[nf][1] + b1v;
            float y2 = acc[nf][2] + b2v, y3 = acc[nf][3] + b3v;
            ls += y0 + y1v + y2 + y3;
            lsq += y0 * y0 + y1v * y1v + y2 * y2 + y3 * y3;
            xsu[p * (CPAD / 2) + (o >> 1)] = cvtpk(y0, y1v);
            xsu[p * (CPAD / 2) + (o >> 1) + 1] = cvtpk(y2, y3);
        }
    }
    __syncthreads();
    // granule-linear dump: lane <-> consecutive 16B granule, fully coalesced
    {
        size_t gb = (size_t)(b * NPIX + pix0) * C_;
#pragma unroll
        for (int k = 0; k < 12; ++k) {
            int g = tid + k * 256;
            int pix = g / 12, cgr = g - pix * 12;
            *reinterpret_cast<short8*>(&ap[gb + (size_t)g * 8]) =
                *reinterpret_cast<short8*>(&xs[pix * CPAD + cgr * 8]);
        }
    }
    ls = waveReduceSum(ls);
    lsq = waveReduceSum(lsq);
    if (l == 0) { red[wv] = ls; red[4 + wv] = lsq; }
    __syncthreads();
    if (tid == 0) {
        atomicAdd(&stats[b], red[0] + red[1] + red[2] + red[3]);
        atomicAdd(&stats[4 + b], red[4] + red[5] + red[6] + red[7]);
    }
}

// ---- K3: staged halo (affine+gelu in regs) + 4 shifted convs -> zb NHWC ----
// WT=32 tile: wave wv owns rows {2wv, 2wv+1}, 4 nf bodies (2 rows x 2 col16).
// mt-outer: 6 weight frags loaded once per mt, feed 4 nf bodies (96 out/thr).
// GN1 finalized inline from raw sums. shifts (s = kb-1):
//   v0 a[h][w-s]  v1 a[h-s][w-s]  v2 a[h-s][w]  v3 a[h-s][w+s]
__global__ __launch_bounds__(256, 2) void k3_main(
    const unsigned short* __restrict__ ap,
    const unsigned short* __restrict__ w21f, const float* __restrict__ b21,
    const unsigned short* __restrict__ w22f, const float* __restrict__ b22,
    const float* __restrict__ gn1w, const float* __restrict__ gn1b,
    unsigned short* __restrict__ zb, float* __restrict__ stats) {
    __shared__ unsigned short as_t[HALO_PX * CPAD];  // 70720 B
    __shared__ float red[8];
    __shared__ float scs[C_], offs[C_];
    int tid = threadIdx.x;
    int wseg = blockIdx.x & 7;
    int hseg = (blockIdx.x >> 3) & 31;
    int b = blockIdx.x >> 8;  // grid = 4*32*8 = 1024
    int l = tid & 63, wv = tid >> 6;
    int h0 = hseg * HT, w0 = wseg * WT;
    // inline GN1 finalize from raw sums (uniform across threads)
    float m1 = stats[b] / GN_N;
    float r1 = rsqrtf(stats[4 + b] / GN_N - m1 * m1 + 1e-5f);
    if (tid < C_) {
        float sc = r1 * gn1w[tid];
        scs[tid] = sc;
        offs[tid] = gn1b[tid] - m1 * sc;
    }
    __syncthreads();
    // --- stage halo: coalesced b128 loads, affine+gelu+border-mask in regs ---
    for (int g = tid; g < TOT_GR; g += 256) {
        int row = g / ROW_GR;
        int rem = g - row * ROW_GR;
        int p = rem / GR_PX;
        int cgr = rem - p * GR_PX;
        int hh = h0 - 1 + row, ww = w0 - 1 + p;
        unsigned short* dst = &as_t[(row * HWT + p) * CPAD + cgr * 8];
        if (((unsigned)hh < (unsigned)H_) && ((unsigned)ww < (unsigned)W_)) {
            short8 raw = *reinterpret_cast<const short8*>(
                &ap[(size_t)(b * NPIX + hh * W_ + ww) * C_ + cgr * 8]);
            float gv[8];
#pragma unroll
            for (int j = 0; j < 8; ++j) {
                int c = cgr * 8 + j;
                gv[j] = gelu_f(fmaf(bf2f((unsigned short)raw[j]), scs[c], offs[c]));
            }
            uint4v pk = {cvtpk(gv[0], gv[1]), cvtpk(gv[2], gv[3]),
                         cvtpk(gv[4], gv[5]), cvtpk(gv[6], gv[7])};
            *reinterpret_cast<uint4v*>(dst) = pk;
        } else {
            *reinterpret_cast<uint4v*>(dst) = (uint4v){0, 0, 0, 0};
        }
    }
    __syncthreads();
    // --- compute: mt outer, weights once; 4 nf bodies read frags from LDS ---
    int bx = l & 15, q = l >> 4, cl = q * 8;
#define FR(R, X0, dx, kb) (*reinterpret_cast<const short8*>( \
        &as_t[((R)*HWT + (dx) + (X0) + bx + 1) * CPAD + cl + (kb)*32]))
    float ls = 0.f, lsq = 0.f;
    for (int mt = 0; mt < 6; ++mt) {
        int m0 = mt * 16;
        short8 aA0 = wfrag(w21f, mt, 0, l);
        short8 aA1 = wfrag(w21f, mt, 1, l);
        short8 aA2 = wfrag(w21f, mt, 2, l);
        short8 aB0 = wfrag(w22f, mt, 0, l);
        short8 aB1 = wfrag(w22f, mt, 1, l);
        short8 aB2 = wfrag(w22f, mt, 2, l);
        const f32x4 bb1 = *reinterpret_cast<const f32x4*>(&b21[m0 + q * 4]);
        const f32x4 bb2 = *reinterpret_cast<const f32x4*>(&b22[m0 + q * 4]);
#pragma unroll
        for (int nf = 0; nf < 4; ++nf) {
            int r = 2 * wv + (nf >> 1);   // output row in tile
            int X0 = (nf & 1) * 16;       // column half
            short8 f0a = FR(r + 1, X0, 1, 0), f0b = FR(r + 2, X0, 1, 0);
            short8 f0c = FR(r + 2, X0, 0, 0), f0d = FR(r + 2, X0, -1, 0);
            short8 fC = FR(r + 1, X0, 0, 1);
            short8 f2a = FR(r + 1, X0, -1, 2), f2b = FR(r, X0, -1, 2);
            short8 f2c = FR(r, X0, 0, 2), f2d = FR(r, X0, 1, 2);
            f32x4 a0 = bb1, a1 = bb1, a2 = bb2, a3 = bb2;
            a0 = mfma16(aA0, f0a, a0);
            a1 = mfma16(aA0, f0b, a1);
            a2 = mfma16(aB0, f0c, a2);
            a3 = mfma16(aB0, f0d, a3);
            a0 = mfma16(aA1, fC, a0);
            a1 = mfma16(aA1, fC, a1);
            a2 = mfma16(aB1, fC, a2);
            a3 = mfma16(aB1, fC, a3);
            a0 = mfma16(aA2, f2a, a0);
            a1 = mfma16(aA2, f2b, a1);
            a2 = mfma16(aB2, f2c, a2);
            a3 = mfma16(aB2, f2d, a3);
            float zv[4];
#pragma unroll
            for (int rg = 0; rg < 4; ++rg) {
                float z0 = gelu_f(a0[rg]) + gelu_f(a1[rg]) +
                           gelu_f(a2[rg]) + gelu_f(a3[rg]);
                zv[rg] = z0;
                ls += z0;
                lsq += z0 * z0;
            }
            uint2v pk;
            pk.x = cvtpk(zv[0], zv[1]);
            pk.y = cvtpk(zv[2], zv[3]);
            size_t zpix = (size_t)(b * NPIX + (h0 + r) * W_ + w0 + X0 + bx) * C_ +
                          q * 4 + m0;
            *reinterpret_cast<uint2v*>(&zb[zpix]) = pk;
        }
    }
#undef FR
    ls = waveReduceSum(ls);
    lsq = waveReduceSum(lsq);
    if (l == 0) { red[wv] = ls; red[4 + wv] = lsq; }
    __syncthreads();
    if (tid == 0) {
        atomicAdd(&stats[8 + b], red[0] + red[1] + red[2] + red[3]);
        atomicAdd(&stats[12 + b], red[4] + red[5] + red[6] + red[7]);
    }
}

// ---- K4b: finalize GN2 + fold affine into W3/b3 (frag-order, per batch) ----
// out = W3*(sc .* z + off) + b3 = (W3*diag(sc))*z + (W3*off + b3)
__global__ void k4b_fold(const float* __restrict__ w3, const float* __restrict__ b3,
                         const float* __restrict__ gn2w, const float* __restrict__ gn2b,
                         const float* __restrict__ stats,
                         unsigned short* __restrict__ w3pf, float* __restrict__ b3p) {
    int b = blockIdx.x;
    int t = threadIdx.x;  // 256 threads
    float mean = stats[8 + b] / GN_N;
    float var = stats[12 + b] / GN_N - mean * mean;
    float r2 = rsqrtf(var + 1e-5f);
#pragma unroll
    for (int k = 0; k < 36; ++k) {
        int idx = t + k * 256;  // 0..9215
        int f = idx >> 3, j = idx & 7;
        int mt = f / 192, rem = f - mt * 192;
        int kb = rem >> 6, l = rem & 63;
        int row = mt * 16 + (l & 15);
        int col = kb * 32 + ((l >> 4) << 3) + j;
        float sc = r2 * gn2w[col];
        w3pf[(size_t)b * WFRAG + idx] = f2bf(w3[row * C_ + col] * sc);
    }
    if (t < C_) {
        float acc = 0.f;
        for (int c = 0; c < C_; ++c) {
            float sc = r2 * gn2w[c];
            float off = gn2b[c] - mean * sc;
            acc = fmaf(w3[t * C_ + c], off, acc);
        }
        b3p[b * C_ + t] = acc + b3[t];
    }
}

// ------- K5: conv3 GEMM (frag-order folded weights; granule-linear stage) ---
__global__ __launch_bounds__(256, 3) void k5_conv3(
    const unsigned short* __restrict__ zb,
    const unsigned short* __restrict__ w3pf, const float* __restrict__ b3p,
    float* __restrict__ out) {
    __shared__ unsigned short zs[256 * CPAD];
    int tid = threadIdx.x;
    int b = blockIdx.x >> 8;
    int pix0 = (blockIdx.x & 255) << 8;
    {
        // block's zb region is one contiguous 96KB span: stream it linearly
        size_t gb = (size_t)(b * NPIX + pix0) * C_;
#pragma unroll
        for (int k = 0; k < 12; ++k) {
            int g = tid + k * 256;
            int pix = g / 12, cgr = g - pix * 12;
            *reinterpret_cast<short8*>(&zs[pix * CPAD + cgr * 8]) =
                *reinterpret_cast<const short8*>(&zb[gb + (size_t)g * 8]);
        }
    }
    __syncthreads();
    int l = tid & 63, wv = tid >> 6;
    int bx = l & 15, q = l >> 4, cl = q * 8;
    short8 bfr[4][3];
#pragma unroll
    for (int nf = 0; nf < 4; ++nf) {
        int p = (4 * wv + nf) * 16 + bx;
#pragma unroll
        for (int kb = 0; kb < 3; ++kb)
            bfr[nf][kb] = *reinterpret_cast<const short8*>(&zs[p * CPAD + kb * 32 + cl]);
    }
    const unsigned short* wbase = w3pf + (size_t)b * WFRAG;
    const float* bb = b3p + b * C_;
    for (int mt = 0; mt < 6; ++mt) {
        int m0 = mt * 16;
        short8 af0 = wfrag(wbase, mt, 0, l);
        short8 af1 = wfrag(wbase, mt, 1, l);
        short8 af2 = wfrag(wbase, mt, 2, l);
        f32x4 acc[4];
#pragma unroll
        for (int nf = 0; nf < 4; ++nf) acc[nf] = (f32x4){0.f, 0.f, 0.f, 0.f};
#pragma unroll
        for (int nf = 0; nf < 4; ++nf) {
            acc[nf] = mfma16(af0, bfr[nf][0], acc[nf]);
            acc[nf] = mfma16(af1, bfr[nf][1], acc[nf]);
            acc[nf] = mfma16(af2, bfr[nf][2], acc[nf]);
        }
        int o = m0 + q * 4;
        float b0 = bb[o], b1v = bb[o + 1], b2v = bb[o + 2], b3v = bb[o + 3];
#pragma unroll
        for (int nf = 0; nf < 4; ++nf) {
            int p = pix0 + (4 * wv + nf) * 16 + bx;
            size_t ob0 = (size_t)(b * C_ + o) * NPIX + p;
            out[ob0] = acc[nf][0] + b0;
            out[ob0 + NPIX] = acc[nf][1] + b1v;
            out[ob0 + 2 * NPIX] = acc[nf][2] + b2v;
            out[ob0 + 3 * NPIX] = acc[nf][3] + b3v;
        }
    }
}

extern "C" void kernel_launch(void* const* d_in, const int* in_sizes, int n_in,
                              void* d_out, int out_size, void* d_ws, size_t ws_size,
                              hipStream_t stream) {
    const float* x = (const float*)d_in[0];
    const float* w1 = (const float*)d_in[1];
    const float* b1 = (const float*)d_in[2];
    const float* w21 = (const float*)d_in[3];
    const float* b21 = (const float*)d_in[4];
    const float* w22 = (const float*)d_in[5];
    const float* b22 = (const float*)d_in[6];
    const float* w3 = (const float*)d_in[7];
    const float* b3 = (const float*)d_in[8];
    const float* gn1w = (const float*)d_in[9];
    const float* gn1b = (const float*)d_in[10];
    const float* gn2w = (const float*)d_in[11];
    const float* gn2b = (const float*)d_in[12];
    float* out = (float*)d_out;
    char* ws = (char*)d_ws;

    const size_t NB = (size_t)B_ * NPIX * C_ * sizeof(unsigned short);  // 50,331,648
    unsigned short* ap = (unsigned short*)ws;
    unsigned short* zb = (unsigned short*)(ws + NB);
    float* stats = (float*)(ws + 2 * NB);  // 32 floats
    unsigned short* wf = (unsigned short*)(ws + 2 * NB + 128);  // 3 frag matrices
    unsigned short* w1f = wf;
    unsigned short* w21f = wf + WFRAG;
    unsigned short* w22f = wf + 2 * WFRAG;
    unsigned short* w3pf = wf + 3 * WFRAG;           // folded W3 (per batch)
    float* b3p = (float*)(w3pf + B_ * WFRAG);        // folded b3 (per batch)

    hipLaunchKernelGGL(k0_prep, dim3(112), dim3(256), 0, stream,
                       w1, w21, w22, wf, stats);
    hipLaunchKernelGGL(k1_conv1, dim3(1024), dim3(256), 0, stream, x, w1f, b1, ap, stats);
    hipLaunchKernelGGL(k3_main, dim3(1024), dim3(256), 0, stream,
                       ap, w21f, b21, w22f, b22, gn1w, gn1b, zb, stats);
    hipLaunchKernelGGL(k4b_fold, dim3(B_), dim3(256), 0, stream,
                       w3, b3, gn2w, gn2b, stats, w3pf, b3p);
    hipLaunchKernelGGL(k5_conv3, dim3(1024), dim3(256), 0, stream,
                       zb, w3pf, b3p, out);
}

// Round 23
// 156.642 us; speedup vs baseline: 1.0672x; 1.0672x over previous
//
#include <hip/hip_runtime.h>
#include <hip/hip_bf16.h>
#include <math.h>

// AxialShift block: conv1x1 -> GN(1) -> GELU -> 4 axial-shift conv1x1 branches
// (gelu, summed) -> GN(1) -> conv1x1.  B=4, C=96, H=W=256, fp32 in/out.
// Round 23: exact revert to r21 (session best, 156.7us). r22's WT32 revisit
// regressed (occupancy 31->19%, write-combining loss: WRITE 55->111MB) --
// 11th falsified theory; this configuration is the practical plateau.
//   k0: weights->bf16 frag-order | k1: conv1+GN1 raw stats -> ap NHWC bf16
//   k3: staged halo (gelu fused) + 4 shifted convs -> zb + GN2 raw stats
//   k4b: finalize GN2 + fold into W3/b3 (frag-order) | k5: conv3 -> d_out

#define B_ 4
#define C_ 96
#define H_ 256
#define W_ 256
#define NPIX (H_ * W_)
#define GN_N ((float)(C_ * NPIX))
#define CPAD 104  // LDS channel stride in shorts (208B: 16B-aligned, ~2-way banks)
#define WFRAG 9216  // shorts per frag-ordered 96x96 matrix (1152 frags x 8)

// k3 tile
#define HT 8
#define WT 16
#define HHT (HT + 2)
#define HWT (WT + 2)
#define HALO_PX (HHT * HWT)   // 180
#define GR_PX 12              // 16B granules per pixel (96 ch bf16)
#define ROW_GR (HWT * GR_PX)  // 216
#define TOT_GR (HHT * ROW_GR) // 2160

typedef __attribute__((ext_vector_type(4))) float f32x4;
typedef __attribute__((ext_vector_type(8))) short short8;
typedef __attribute__((ext_vector_type(2))) unsigned int uint2v;
typedef __attribute__((ext_vector_type(4))) unsigned int uint4v;

__device__ __forceinline__ float bf2f(unsigned short u) {
    return __uint_as_float(((unsigned int)u) << 16);
}
__device__ __forceinline__ unsigned short f2bf(float v) {
    unsigned int u = __float_as_uint(v);
    unsigned int r = (u + 0x7FFFu + ((u >> 16) & 1u)) >> 16;
    return (unsigned short)r;
}
// pack two f32 -> two bf16 (RNE) in one op
__device__ __forceinline__ unsigned int cvtpk(float lo, float hi) {
    unsigned int r;
    asm("v_cvt_pk_bf16_f32 %0, %1, %2" : "=v"(r) : "v"(lo), "v"(hi));
    return r;
}

__device__ __forceinline__ float gelu_f(float v) {
    // sigmoid-approx gelu: v * sigmoid(1.702 v) = v * rcp(1 + 2^(-2.455467 v))
    float e = __builtin_amdgcn_exp2f(v * -2.455467f);
    return v * __builtin_amdgcn_rcpf(e + 1.0f);
}

__device__ __forceinline__ float waveReduceSum(float v) {
#pragma unroll
    for (int off = 32; off > 0; off >>= 1) v += __shfl_down(v, off);
    return v;
}

__device__ __forceinline__ f32x4 mfma16(short8 a, short8 b, f32x4 c) {
    return __builtin_amdgcn_mfma_f32_16x16x32_bf16(a, b, c, 0, 0, 0);
}

// coalesced weight-frag load: uniform base + lane*16B
__device__ __forceinline__ short8 wfrag(const unsigned short* __restrict__ wf,
                                        int mt, int kb, int l) {
    return *reinterpret_cast<const short8*>(wf + (((mt * 3 + kb) << 6) + l) * 8);
}

// ------ K0: weights -> bf16 in A-frag order; zero stats ------
// frag f=(mt*3+kb)*64+l, elem j:  w[mt*16+(l&15)][kb*32+(l>>4)*8+j]
__global__ void k0_prep(const float* __restrict__ w1, const float* __restrict__ w21,
                        const float* __restrict__ w22,
                        unsigned short* __restrict__ wf, float* __restrict__ stats) {
    int t = blockIdx.x * 256 + threadIdx.x;
    if (blockIdx.x == 0 && threadIdx.x < 16) stats[threadIdx.x] = 0.f;
    if (t >= 3 * WFRAG) return;
    int m = t / WFRAG, rm = t - m * WFRAG;
    int f = rm >> 3, j = rm & 7;
    int mt = f / 192, rem = f - mt * 192;
    int kb = rem >> 6, l = rem & 63;
    int row = mt * 16 + (l & 15);
    int col = kb * 32 + ((l >> 4) << 3) + j;
    const float* src = (m == 0) ? w1 : (m == 1) ? w21 : w22;
    wf[t] = f2bf(src[row * C_ + col]);
}

// ------- K1: conv1 (MFMA) + GN1 raw stats -> ap NHWC bf16 (pre-gelu) -------
__global__ __launch_bounds__(256, 3) void k1_conv1(
    const float* __restrict__ x, const unsigned short* __restrict__ w1f,
    const float* __restrict__ b1, unsigned short* __restrict__ ap,
    float* __restrict__ stats) {
    __shared__ unsigned short xs[256 * CPAD];
    __shared__ float red[8];
    int tid = threadIdx.x;
    int b = blockIdx.x >> 8;
    int h = blockIdx.x & 255;
    int pix0 = h << 8;
    size_t xbase = (size_t)b * C_ * NPIX + pix0 + tid;
    int lb = tid * CPAD;
    // staging: 3 batches of 32 loads (3 latency events instead of 12)
#pragma unroll
    for (int cc = 0; cc < C_; cc += 32) {
        float f[32];
#pragma unroll
        for (int j = 0; j < 32; ++j) f[j] = x[xbase + (size_t)(cc + j) * NPIX];
#pragma unroll
        for (int p8 = 0; p8 < 4; ++p8) {
            uint4v pk = {cvtpk(f[p8 * 8 + 0], f[p8 * 8 + 1]),
                         cvtpk(f[p8 * 8 + 2], f[p8 * 8 + 3]),
                         cvtpk(f[p8 * 8 + 4], f[p8 * 8 + 5]),
                         cvtpk(f[p8 * 8 + 6], f[p8 * 8 + 7])};
            *reinterpret_cast<uint4v*>(&xs[lb + cc + p8 * 8]) = pk;
        }
    }
    __syncthreads();
    int l = tid & 63, wv = tid >> 6;
    int bx = l & 15, q = l >> 4, cl = q * 8;
    short8 bfr[4][3];
#pragma unroll
    for (int nf = 0; nf < 4; ++nf) {
        int p = (4 * wv + nf) * 16 + bx;
#pragma unroll
        for (int kb = 0; kb < 3; ++kb)
            bfr[nf][kb] = *reinterpret_cast<const short8*>(&xs[p * CPAD + kb * 32 + cl]);
    }
    unsigned int* xsu = reinterpret_cast<unsigned int*>(xs);
    float ls = 0.f, lsq = 0.f;
    for (int mt = 0; mt < 6; ++mt) {
        int m0 = mt * 16;
        short8 af[3];
#pragma unroll
        for (int kb = 0; kb < 3; ++kb) af[kb] = wfrag(w1f, mt, kb, l);
        f32x4 acc[4];
#pragma unroll
        for (int nf = 0; nf < 4; ++nf) acc[nf] = (f32x4){0.f, 0.f, 0.f, 0.f};
#pragma unroll
        for (int nf = 0; nf < 4; ++nf)
#pragma unroll
            for (int kb = 0; kb < 3; ++kb)
                acc[nf] = mfma16(af[kb], bfr[nf][kb], acc[nf]);
        int o = m0 + q * 4;
        float b0 = b1[o], b1v = b1[o + 1], b2v = b1[o + 2], b3v = b1[o + 3];
#pragma unroll
        for (int nf = 0; nf < 4; ++nf) {
            int p = (4 * wv + nf) * 16 + bx;  // own wave stripe: race-free
            float y0 = acc[nf][0] + b0, y1v = acc[nf][1] + b1v;
            float y2 = acc[nf][2] + b2v, y3 = acc[nf][3] + b3v;
            ls += y0 + y1v + y2 + y3;
            lsq += y0 * y0 + y1v * y1v + y2 * y2 + y3 * y3;
            xsu[p * (CPAD / 2) + (o >> 1)] = cvtpk(y0, y1v);
            xsu[p * (CPAD / 2) + (o >> 1) + 1] = cvtpk(y2, y3);
        }
    }
    __syncthreads();
    // granule-linear dump: lane <-> consecutive 16B granule, fully coalesced
    {
        size_t gb = (size_t)(b * NPIX + pix0) * C_;
#pragma unroll
        for (int k = 0; k < 12; ++k) {
            int g = tid + k * 256;
            int pix = g / 12, cgr = g - pix * 12;
            *reinterpret_cast<short8*>(&ap[gb + (size_t)g * 8]) =
                *reinterpret_cast<short8*>(&xs[pix * CPAD + cgr * 8]);
        }
    }
    ls = waveReduceSum(ls);
    lsq = waveReduceSum(lsq);
    if (l == 0) { red[wv] = ls; red[4 + wv] = lsq; }
    __syncthreads();
    if (tid == 0) {
        atomicAdd(&stats[b], red[0] + red[1] + red[2] + red[3]);
        atomicAdd(&stats[4 + b], red[4] + red[5] + red[6] + red[7]);
    }
}

// ---- K3: staged halo (affine+gelu in regs) + 4 shifted convs -> zb NHWC ----
// GN1 finalized inline from raw sums (k2_fin eliminated). mt-outer schedule.
// shifts (s = kb-1): v0 a[h][w-s]  v1 a[h-s][w-s]  v2 a[h-s][w]  v3 a[h-s][w+s]
__global__ __launch_bounds__(256, 4) void k3_main(
    const unsigned short* __restrict__ ap,
    const unsigned short* __restrict__ w21f, const float* __restrict__ b21,
    const unsigned short* __restrict__ w22f, const float* __restrict__ b22,
    const float* __restrict__ gn1w, const float* __restrict__ gn1b,
    unsigned short* __restrict__ zb, float* __restrict__ stats) {
    __shared__ unsigned short as_t[HALO_PX * CPAD];  // 37440 B
    __shared__ float red[8];
    __shared__ float scs[C_], offs[C_];
    int tid = threadIdx.x;
    int wseg = blockIdx.x & 15;
    int hseg = (blockIdx.x >> 4) & 31;
    int b = blockIdx.x >> 9;  // grid = 4*32*16 = 2048
    int l = tid & 63, wv = tid >> 6;
    int h0 = hseg * HT, w0 = wseg * WT;
    // inline GN1 finalize from raw sums (uniform across threads)
    float m1 = stats[b] / GN_N;
    float r1 = rsqrtf(stats[4 + b] / GN_N - m1 * m1 + 1e-5f);
    if (tid < C_) {
        float sc = r1 * gn1w[tid];
        scs[tid] = sc;
        offs[tid] = gn1b[tid] - m1 * sc;
    }
    __syncthreads();
    // --- stage halo: coalesced b128 loads, affine+gelu+border-mask in regs ---
    for (int g = tid; g < TOT_GR; g += 256) {
        int row = g / ROW_GR;
        int rem = g - row * ROW_GR;
        int p = rem / GR_PX;
        int cgr = rem - p * GR_PX;
        int hh = h0 - 1 + row, ww = w0 - 1 + p;
        unsigned short* dst = &as_t[(row * HWT + p) * CPAD + cgr * 8];
        if (((unsigned)hh < (unsigned)H_) && ((unsigned)ww < (unsigned)W_)) {
            short8 raw = *reinterpret_cast<const short8*>(
                &ap[(size_t)(b * NPIX + hh * W_ + ww) * C_ + cgr * 8]);
            float gv[8];
#pragma unroll
            for (int j = 0; j < 8; ++j) {
                int c = cgr * 8 + j;
                gv[j] = gelu_f(fmaf(bf2f((unsigned short)raw[j]), scs[c], offs[c]));
            }
            uint4v pk = {cvtpk(gv[0], gv[1]), cvtpk(gv[2], gv[3]),
                         cvtpk(gv[4], gv[5]), cvtpk(gv[6], gv[7])};
            *reinterpret_cast<uint4v*>(dst) = pk;
        } else {
            *reinterpret_cast<uint4v*>(dst) = (uint4v){0, 0, 0, 0};
        }
    }
    __syncthreads();
    // --- compute: mt outer, weights once; nf inner reads frags from LDS ---
    int bx = l & 15, q = l >> 4, cl = q * 8;
    int Xb = (bx + 1) * CPAD + cl;
#define FR(R, dx, kb) (*reinterpret_cast<const short8*>( \
        &as_t[((R)*HWT + (dx)) * CPAD + Xb + (kb)*32]))
    float ls = 0.f, lsq = 0.f;
    size_t zrow0 = (size_t)(b * NPIX + (h0 + 2 * wv) * W_ + w0 + bx) * C_ + q * 4;
    for (int mt = 0; mt < 6; ++mt) {
        int m0 = mt * 16;
        short8 aA0 = wfrag(w21f, mt, 0, l);
        short8 aA1 = wfrag(w21f, mt, 1, l);
        short8 aA2 = wfrag(w21f, mt, 2, l);
        short8 aB0 = wfrag(w22f, mt, 0, l);
        short8 aB1 = wfrag(w22f, mt, 1, l);
        short8 aB2 = wfrag(w22f, mt, 2, l);
        const f32x4 bb1 = *reinterpret_cast<const f32x4*>(&b21[m0 + q * 4]);
        const f32x4 bb2 = *reinterpret_cast<const f32x4*>(&b22[m0 + q * 4]);
#pragma unroll
        for (int nf = 0; nf < 2; ++nf) {
            int r = 2 * wv + nf;  // output row in tile
            short8 f0a = FR(r + 1, 1, 0), f0b = FR(r + 2, 1, 0);
            short8 f0c = FR(r + 2, 0, 0), f0d = FR(r + 2, -1, 0);
            short8 fC = FR(r + 1, 0, 1);
            short8 f2a = FR(r + 1, -1, 2), f2b = FR(r, -1, 2);
            short8 f2c = FR(r, 0, 2), f2d = FR(r, 1, 2);
            f32x4 a0 = bb1, a1 = bb1, a2 = bb2, a3 = bb2;
            a0 = mfma16(aA0, f0a, a0);
            a1 = mfma16(aA0, f0b, a1);
            a2 = mfma16(aB0, f0c, a2);
            a3 = mfma16(aB0, f0d, a3);
            a0 = mfma16(aA1, fC, a0);
            a1 = mfma16(aA1, fC, a1);
            a2 = mfma16(aB1, fC, a2);
            a3 = mfma16(aB1, fC, a3);
            a0 = mfma16(aA2, f2a, a0);
            a1 = mfma16(aA2, f2b, a1);
            a2 = mfma16(aB2, f2c, a2);
            a3 = mfma16(aB2, f2d, a3);
            float zv[4];
#pragma unroll
            for (int rg = 0; rg < 4; ++rg) {
                float z0 = gelu_f(a0[rg]) + gelu_f(a1[rg]) +
                           gelu_f(a2[rg]) + gelu_f(a3[rg]);
                zv[rg] = z0;
                ls += z0;
                lsq += z0 * z0;
            }
            uint2v pk;
            pk.x = cvtpk(zv[0], zv[1]);
            pk.y = cvtpk(zv[2], zv[3]);
            *reinterpret_cast<uint2v*>(
                &zb[zrow0 + (size_t)nf * W_ * C_ + m0]) = pk;
        }
    }
#undef FR
    ls = waveReduceSum(ls);
    lsq = waveReduceSum(lsq);
    if (l == 0) { red[wv] = ls; red[4 + wv] = lsq; }
    __syncthreads();
    if (tid == 0) {
        atomicAdd(&stats[8 + b], red[0] + red[1] + red[2] + red[3]);
        atomicAdd(&stats[12 + b], red[4] + red[5] + red[6] + red[7]);
    }
}

// ---- K4b: finalize GN2 + fold affine into W3/b3 (frag-order, per batch) ----
// out = W3*(sc .* z + off) + b3 = (W3*diag(sc))*z + (W3*off + b3)
__global__ void k4b_fold(const float* __restrict__ w3, const float* __restrict__ b3,
                         const float* __restrict__ gn2w, const float* __restrict__ gn2b,
                         const float* __restrict__ stats,
                         unsigned short* __restrict__ w3pf, float* __restrict__ b3p) {
    int b = blockIdx.x;
    int t = threadIdx.x;  // 256 threads
    float mean = stats[8 + b] / GN_N;
    float var = stats[12 + b] / GN_N - mean * mean;
    float r2 = rsqrtf(var + 1e-5f);
#pragma unroll
    for (int k = 0; k < 36; ++k) {
        int idx = t + k * 256;  // 0..9215
        int f = idx >> 3, j = idx & 7;
        int mt = f / 192, rem = f - mt * 192;
        int kb = rem >> 6, l = rem & 63;
        int row = mt * 16 + (l & 15);
        int col = kb * 32 + ((l >> 4) << 3) + j;
        float sc = r2 * gn2w[col];
        w3pf[(size_t)b * WFRAG + idx] = f2bf(w3[row * C_ + col] * sc);
    }
    if (t < C_) {
        float acc = 0.f;
        for (int c = 0; c < C_; ++c) {
            float sc = r2 * gn2w[c];
            float off = gn2b[c] - mean * sc;
            acc = fmaf(w3[t * C_ + c], off, acc);
        }
        b3p[b * C_ + t] = acc + b3[t];
    }
}

// ------- K5: conv3 GEMM (frag-order folded weights; granule-linear stage) ---
__global__ __launch_bounds__(256, 3) void k5_conv3(
    const unsigned short* __restrict__ zb,
    const unsigned short* __restrict__ w3pf, const float* __restrict__ b3p,
    float* __restrict__ out) {
    __shared__ unsigned short zs[256 * CPAD];
    int tid = threadIdx.x;
    int b = blockIdx.x >> 8;
    int pix0 = (blockIdx.x & 255) << 8;
    {
        // block's zb region is one contiguous 96KB span: stream it linearly
        size_t gb = (size_t)(b * NPIX + pix0) * C_;
#pragma unroll
        for (int k = 0; k < 12; ++k) {
            int g = tid + k * 256;
            int pix = g / 12, cgr = g - pix * 12;
            *reinterpret_cast<short8*>(&zs[pix * CPAD + cgr * 8]) =
                *reinterpret_cast<const short8*>(&zb[gb + (size_t)g * 8]);
        }
    }
    __syncthreads();
    int l = tid & 63, wv = tid >> 6;
    int bx = l & 15, q = l >> 4, cl = q * 8;
    short8 bfr[4][3];
#pragma unroll
    for (int nf = 0; nf < 4; ++nf) {
        int p = (4 * wv + nf) * 16 + bx;
#pragma unroll
        for (int kb = 0; kb < 3; ++kb)
            bfr[nf][kb] = *reinterpret_cast<const short8*>(&zs[p * CPAD + kb * 32 + cl]);
    }
    const unsigned short* wbase = w3pf + (size_t)b * WFRAG;
    const float* bb = b3p + b * C_;
    for (int mt = 0; mt < 6; ++mt) {
        int m0 = mt * 16;
        short8 af0 = wfrag(wbase, mt, 0, l);
        short8 af1 = wfrag(wbase, mt, 1, l);
        short8 af2 = wfrag(wbase, mt, 2, l);
        f32x4 acc[4];
#pragma unroll
        for (int nf = 0; nf < 4; ++nf) acc[nf] = (f32x4){0.f, 0.f, 0.f, 0.f};
#pragma unroll
        for (int nf = 0; nf < 4; ++nf) {
            acc[nf] = mfma16(af0, bfr[nf][0], acc[nf]);
            acc[nf] = mfma16(af1, bfr[nf][1], acc[nf]);
            acc[nf] = mfma16(af2, bfr[nf][2], acc[nf]);
        }
        int o = m0 + q * 4;
        float b0 = bb[o], b1v = bb[o + 1], b2v = bb[o + 2], b3v = bb[o + 3];
#pragma unroll
        for (int nf = 0; nf < 4; ++nf) {
            int p = pix0 + (4 * wv + nf) * 16 + bx;
            size_t ob0 = (size_t)(b * C_ + o) * NPIX + p;
            out[ob0] = acc[nf][0] + b0;
            out[ob0 + NPIX] = acc[nf][1] + b1v;
            out[ob0 + 2 * NPIX] = acc[nf][2] + b2v;
            out[ob0 + 3 * NPIX] = acc[nf][3] + b3v;
        }
    }
}

extern "C" void kernel_launch(void* const* d_in, const int* in_sizes, int n_in,
                              void* d_out, int out_size, void* d_ws, size_t ws_size,
                              hipStream_t stream) {
    const float* x = (const float*)d_in[0];
    const float* w1 = (const float*)d_in[1];
    const float* b1 = (const float*)d_in[2];
    const float* w21 = (const float*)d_in[3];
    const float* b21 = (const float*)d_in[4];
    const float* w22 = (const float*)d_in[5];
    const float* b22 = (const float*)d_in[6];
    const float* w3 = (const float*)d_in[7];
    const float* b3 = (const float*)d_in[8];
    const float* gn1w = (const float*)d_in[9];
    const float* gn1b = (const float*)d_in[10];
    const float* gn2w = (const float*)d_in[11];
    const float* gn2b = (const float*)d_in[12];
    float* out = (float*)d_out;
    char* ws = (char*)d_ws;

    const size_t NB = (size_t)B_ * NPIX * C_ * sizeof(unsigned short);  // 50,331,648
    unsigned short* ap = (unsigned short*)ws;
    unsigned short* zb = (unsigned short*)(ws + NB);
    float* stats = (float*)(ws + 2 * NB);  // 32 floats
    unsigned short* wf = (unsigned short*)(ws + 2 * NB + 128);  // 3 frag matrices
    unsigned short* w1f = wf;
    unsigned short* w21f = wf + WFRAG;
    unsigned short* w22f = wf + 2 * WFRAG;
    unsigned short* w3pf = wf + 3 * WFRAG;           // folded W3 (per batch)
    float* b3p = (float*)(w3pf + B_ * WFRAG);        // folded b3 (per batch)

    hipLaunchKernelGGL(k0_prep, dim3(112), dim3(256), 0, stream,
                       w1, w21, w22, wf, stats);
    hipLaunchKernelGGL(k1_conv1, dim3(1024), dim3(256), 0, stream, x, w1f, b1, ap, stats);
    hipLaunchKernelGGL(k3_main, dim3(2048), dim3(256), 0, stream,
                       ap, w21f, b21, w22f, b22, gn1w, gn1b, zb, stats);
    hipLaunchKernelGGL(k4b_fold, dim3(B_), dim3(256), 0, stream,
                       w3, b3, gn2w, gn2b, stats, w3pf, b3p);
    hipLaunchKernelGGL(k5_conv3, dim3(1024), dim3(256), 0, stream,
                       zb, w3pf, b3p, out);
}